// Round 1
// baseline (3648.936 us; speedup 1.0000x reference)
//
#include <hip/hip_runtime.h>

// HGIN_classifier: two relational-GIN layers (R=2), ReLU between.
// Plan:
//   K0 zero_f4:   zero agg buffer in ws
//   K1 scatter1:  agg[(dst*2+et)*128+:] += x[src*128+:]   (fp32 HW atomics, 32 lanes/edge)
//   K2 gemm1:     h = relu([x|agg] @ [W1s;W1r] + b1)  (virtual K=384 SGEMM, 64x256 tile)
//                 epilogue (h never stored): z2[i][r][o]=h.W2r[r,:,o]; out[i]=h.W2s+b2
//   K3 scatter2:  out[dst*2+:] += z2[src*4+et*2+:]     (8 B/edge, L2-resident table)

constexpr int NN  = 100000;
constexpr int D_IN = 128;

__global__ void zero_f4(float4* __restrict__ p, int n4) {
  int i = blockIdx.x * blockDim.x + threadIdx.x;
  if (i < n4) p[i] = make_float4(0.f, 0.f, 0.f, 0.f);
}

// 32 threads per edge, each handles one float4 chunk of the 128-wide row.
__global__ void scatter1(const float* __restrict__ x,
                         const int* __restrict__ src,
                         const int* __restrict__ dst,
                         const int* __restrict__ et,
                         float* __restrict__ agg, int E) {
  int tid = blockIdx.x * blockDim.x + threadIdx.x;
  int e = tid >> 5;
  if (e >= E) return;
  int c = tid & 31;
  int s = src[e], d = dst[e], r = et[e];
  float4 v = *(const float4*)(x + (long)s * D_IN + c * 4);
  float* a = agg + ((long)d * 2 + r) * D_IN + c * 4;
  unsafeAtomicAdd(a + 0, v.x);
  unsafeAtomicAdd(a + 1, v.y);
  unsafeAtomicAdd(a + 2, v.z);
  unsafeAtomicAdd(a + 3, v.w);
}

// Virtual A[i][k]: k<128 -> x[i*128+k], else agg[i*256+(k-128)]
// Virtual W[k][j]: k<128 -> w1s[k*256+j], else w1r[(k-128)*256+j]
// Block: 256 threads = (tx 0..31 -> 8 cols each, ty 0..7 -> 8 rows each), tile 64x256.
__global__ void gemm1(const float* __restrict__ x,
                      const float* __restrict__ agg,
                      const float* __restrict__ w1s,
                      const float* __restrict__ w1r,
                      const float* __restrict__ b1,
                      const float* __restrict__ w2s,
                      const float* __restrict__ w2r,
                      const float* __restrict__ b2,
                      float* __restrict__ z2,
                      float* __restrict__ out) {
  __shared__ float As[16][64];
  __shared__ float Bs[16][256];
  const int t = threadIdx.x;
  const int tx = t & 31, ty = t >> 5;
  const long rowBase = (long)blockIdx.x * 64;
  const int lr = t >> 2;          // 0..63: tile row this thread stages
  const int lk = (t & 3) * 4;     // k offset (float4) within 16-wide k-tile
  const long grow = rowBase + lr;
  const bool rv = grow < NN;

  float acc[8][8];
  #pragma unroll
  for (int m = 0; m < 8; ++m)
    #pragma unroll
    for (int n = 0; n < 8; ++n) acc[m][n] = 0.f;

  for (int kt = 0; kt < 384; kt += 16) {
    float4 av = make_float4(0.f, 0.f, 0.f, 0.f);
    if (rv) {
      int k0 = kt + lk;
      const float* ap = (k0 < D_IN) ? (x + grow * D_IN + k0)
                                    : (agg + grow * (2 * D_IN) + (k0 - D_IN));
      av = *(const float4*)ap;
    }
    float4 bv[4];
    #pragma unroll
    for (int u = 0; u < 4; ++u) {
      int flat = u * 1024 + t * 4;
      int k = flat >> 8, j = flat & 255;
      int vk = kt + k;
      const float* bp = (vk < D_IN) ? (w1s + (long)vk * 256 + j)
                                    : (w1r + (long)(vk - D_IN) * 256 + j);
      bv[u] = *(const float4*)bp;
    }
    __syncthreads();
    As[lk + 0][lr] = av.x;
    As[lk + 1][lr] = av.y;
    As[lk + 2][lr] = av.z;
    As[lk + 3][lr] = av.w;
    #pragma unroll
    for (int u = 0; u < 4; ++u) {
      int flat = u * 1024 + t * 4;
      int k = flat >> 8, j = flat & 255;
      *(float4*)&Bs[k][j] = bv[u];
    }
    __syncthreads();
    #pragma unroll
    for (int k = 0; k < 16; ++k) {
      float a[8], b[8];
      #pragma unroll
      for (int m = 0; m < 8; ++m) a[m] = As[k][ty * 8 + m];
      #pragma unroll
      for (int n = 0; n < 8; ++n) b[n] = Bs[k][tx * 8 + n];
      #pragma unroll
      for (int m = 0; m < 8; ++m)
        #pragma unroll
        for (int n = 0; n < 8; ++n)
          acc[m][n] = fmaf(a[m], b[n], acc[m][n]);
    }
  }

  // Epilogue: h = relu(acc + b1); per-row 6 dots (4 z2 + 2 self), reduce over tx.
  float zp[8][6];
  #pragma unroll
  for (int m = 0; m < 8; ++m)
    #pragma unroll
    for (int p = 0; p < 6; ++p) zp[m][p] = 0.f;

  #pragma unroll
  for (int n = 0; n < 8; ++n) {
    int col = tx * 8 + n;
    float bb = b1[col];
    float c0 = w2r[col * 2 + 0];        // w2r shape (2,256,2)
    float c1 = w2r[col * 2 + 1];
    float c2 = w2r[512 + col * 2 + 0];
    float c3 = w2r[512 + col * 2 + 1];
    float c4 = w2s[col * 2 + 0];        // w2s shape (256,2)
    float c5 = w2s[col * 2 + 1];
    #pragma unroll
    for (int m = 0; m < 8; ++m) {
      float h = acc[m][n] + bb;
      h = h > 0.f ? h : 0.f;
      zp[m][0] = fmaf(h, c0, zp[m][0]);
      zp[m][1] = fmaf(h, c1, zp[m][1]);
      zp[m][2] = fmaf(h, c2, zp[m][2]);
      zp[m][3] = fmaf(h, c3, zp[m][3]);
      zp[m][4] = fmaf(h, c4, zp[m][4]);
      zp[m][5] = fmaf(h, c5, zp[m][5]);
    }
  }
  // reduce across the 32 tx-lanes (threads sharing the same 8 rows)
  #pragma unroll
  for (int m = 0; m < 8; ++m)
    #pragma unroll
    for (int p = 0; p < 6; ++p) {
      float v = zp[m][p];
      #pragma unroll
      for (int o = 16; o >= 1; o >>= 1) v += __shfl_xor(v, o, 32);
      zp[m][p] = v;
    }
  if (tx == 0) {
    float b20 = b2[0], b21 = b2[1];
    #pragma unroll
    for (int m = 0; m < 8; ++m) {
      long row = rowBase + ty * 8 + m;
      if (row < NN) {
        z2[row * 4 + 0] = zp[m][0];
        z2[row * 4 + 1] = zp[m][1];
        z2[row * 4 + 2] = zp[m][2];
        z2[row * 4 + 3] = zp[m][3];
        out[row * 2 + 0] = zp[m][4] + b20;
        out[row * 2 + 1] = zp[m][5] + b21;
      }
    }
  }
}

__global__ void scatter2(const float* __restrict__ z2,
                         const int* __restrict__ src,
                         const int* __restrict__ dst,
                         const int* __restrict__ et,
                         float* __restrict__ out, int E) {
  int e = blockIdx.x * blockDim.x + threadIdx.x;
  if (e >= E) return;
  int s = src[e], d = dst[e], r = et[e];
  float2 v = *(const float2*)(z2 + (long)s * 4 + r * 2);
  unsafeAtomicAdd(out + d * 2 + 0, v.x);
  unsafeAtomicAdd(out + d * 2 + 1, v.y);
}

extern "C" void kernel_launch(void* const* d_in, const int* in_sizes, int n_in,
                              void* d_out, int out_size, void* d_ws, size_t ws_size,
                              hipStream_t stream) {
  const float* x   = (const float*)d_in[0];
  const int*   ei  = (const int*)d_in[1];   // (2,E): src then dst
  const int*   et  = (const int*)d_in[2];
  const float* w1s = (const float*)d_in[3];
  const float* w1r = (const float*)d_in[4];
  const float* b1  = (const float*)d_in[5];
  const float* w2s = (const float*)d_in[6];
  const float* w2r = (const float*)d_in[7];
  const float* b2  = (const float*)d_in[8];
  float* out = (float*)d_out;
  const int E = in_sizes[2];
  const int* src = ei;
  const int* dst = ei + E;

  float* agg = (float*)d_ws;                    // NN*256 floats (102.4 MB)
  float* z2  = agg + (long)NN * 256;            // NN*4 floats (1.6 MB)

  int n4 = NN * 256 / 4;
  zero_f4<<<(n4 + 255) / 256, 256, 0, stream>>>((float4*)agg, n4);

  long thr1 = (long)E * 32;
  scatter1<<<(int)((thr1 + 255) / 256), 256, 0, stream>>>(x, src, dst, et, agg, E);

  gemm1<<<(NN + 63) / 64, 256, 0, stream>>>(x, agg, w1s, w1r, b1, w2s, w2r, b2, z2, out);

  scatter2<<<(E + 255) / 256, 256, 0, stream>>>(z2, src, dst, et, out, E);
}

// Round 2
// 1156.204 us; speedup vs baseline: 3.1560x; 3.1560x over previous
//
#include <hip/hip_runtime.h>

// HGIN_classifier: two relational-GIN layers (R=2), ReLU between.
// R2 plan: kill the fp32-atomic scatter (76 G atomics/s ceiling, 2.7 ms) by
// building CSR on-device and gathering:
//   zero_i -> hist -> scan1/scan2/scan3 -> reorder   (int atomics only, L2-resident)
//   aggregate: 1 wave/node, gather x[src] rows, write agg once (no zero pass)
//   gemm1:     h = relu([x|agg] @ [W1s;W1r] + b1) fused epilogue -> z2, out(self)
//   gather2:   out[n] += sum_r sum_{src in seg(n,r)} z2[src][r]  (no atomics)
// Fallback to R1 atomic path if ws_size < CSR budget (R1 proved ws >= 104 MB).

constexpr int NN   = 100000;
constexpr int D_IN = 128;
constexpr int NR   = NN * 2;                 // (node, relation) segments
constexpr int SCAN_BLKS = (NR + 255) / 256;  // 782

__global__ void zero_f4(float4* __restrict__ p, int n4) {
  int i = blockIdx.x * blockDim.x + threadIdx.x;
  if (i < n4) p[i] = make_float4(0.f, 0.f, 0.f, 0.f);
}

__global__ void zero_i(int* __restrict__ p, int n) {
  int i = blockIdx.x * blockDim.x + threadIdx.x;
  if (i < n) p[i] = 0;
}

__global__ void hist(const int* __restrict__ dst, const int* __restrict__ et,
                     int* __restrict__ cnt, int E) {
  int e = blockIdx.x * blockDim.x + threadIdx.x;
  if (e >= E) return;
  atomicAdd(&cnt[dst[e] * 2 + et[e]], 1);
}

// exclusive scan of cnt[NR] in place, block-level; partials[b] = block sum
__global__ void scan1(int* __restrict__ cnt, int* __restrict__ partials) {
  __shared__ int s[256];
  int tid = threadIdx.x;
  int i = blockIdx.x * 256 + tid;
  int v = (i < NR) ? cnt[i] : 0;
  s[tid] = v;
  __syncthreads();
  #pragma unroll
  for (int o = 1; o < 256; o <<= 1) {
    int t = (tid >= o) ? s[tid - o] : 0;
    __syncthreads();
    s[tid] += t;
    __syncthreads();
  }
  if (i < NR) cnt[i] = s[tid] - v;          // exclusive within block
  if (tid == 255) partials[blockIdx.x] = s[255];
}

__global__ void scan2(int* __restrict__ partials) {  // 1 block, 1024 threads
  __shared__ int s[1024];
  int tid = threadIdx.x;
  int v = (tid < SCAN_BLKS) ? partials[tid] : 0;
  s[tid] = v;
  __syncthreads();
  #pragma unroll
  for (int o = 1; o < 1024; o <<= 1) {
    int t = (tid >= o) ? s[tid - o] : 0;
    __syncthreads();
    s[tid] += t;
    __syncthreads();
  }
  partials[tid] = s[tid] - v;               // exclusive
}

__global__ void scan3(int* __restrict__ cnt, const int* __restrict__ partials) {
  int i = blockIdx.x * 256 + threadIdx.x;
  if (i < NR) cnt[i] += partials[blockIdx.x];
}

// After reorder, off[seg] has been bumped by deg(seg): off[seg] == segment END.
// Segment start = (seg==0) ? 0 : off[seg-1].
__global__ void reorder(const int* __restrict__ src, const int* __restrict__ dst,
                        const int* __restrict__ et, int* __restrict__ off,
                        int* __restrict__ srcs, int E) {
  int e = blockIdx.x * blockDim.x + threadIdx.x;
  if (e >= E) return;
  int seg = dst[e] * 2 + et[e];
  int p = atomicAdd(&off[seg], 1);
  srcs[p] = src[e];
}

// One wave (64 lanes) per node; lane l accumulates columns [2l, 2l+1].
__global__ void aggregate(const float* __restrict__ x, const int* __restrict__ off,
                          const int* __restrict__ srcs, float* __restrict__ agg) {
  int w = (blockIdx.x * blockDim.x + threadIdx.x) >> 6;
  if (w >= NN) return;
  int lane = threadIdx.x & 63;
  int e0 = (w == 0) ? 0 : off[2 * w - 1];
  int e1 = off[2 * w];
  int e2 = off[2 * w + 1];
  float2 a0 = make_float2(0.f, 0.f), a1 = make_float2(0.f, 0.f);
  for (int e = e0; e < e1; ++e) {
    int s = srcs[e];
    float2 v = *(const float2*)(x + (long)s * D_IN + lane * 2);
    a0.x += v.x; a0.y += v.y;
  }
  for (int e = e1; e < e2; ++e) {
    int s = srcs[e];
    float2 v = *(const float2*)(x + (long)s * D_IN + lane * 2);
    a1.x += v.x; a1.y += v.y;
  }
  float* row = agg + (long)w * 256;
  *(float2*)(row + lane * 2) = a0;
  *(float2*)(row + 128 + lane * 2) = a1;
}

// ---- layer-1 GEMM + fused layer-2 transform (unchanged from R1) ----
__global__ void gemm1(const float* __restrict__ x,
                      const float* __restrict__ agg,
                      const float* __restrict__ w1s,
                      const float* __restrict__ w1r,
                      const float* __restrict__ b1,
                      const float* __restrict__ w2s,
                      const float* __restrict__ w2r,
                      const float* __restrict__ b2,
                      float* __restrict__ z2,
                      float* __restrict__ out) {
  __shared__ float As[16][64];
  __shared__ float Bs[16][256];
  const int t = threadIdx.x;
  const int tx = t & 31, ty = t >> 5;
  const long rowBase = (long)blockIdx.x * 64;
  const int lr = t >> 2;
  const int lk = (t & 3) * 4;
  const long grow = rowBase + lr;
  const bool rv = grow < NN;

  float acc[8][8];
  #pragma unroll
  for (int m = 0; m < 8; ++m)
    #pragma unroll
    for (int n = 0; n < 8; ++n) acc[m][n] = 0.f;

  for (int kt = 0; kt < 384; kt += 16) {
    float4 av = make_float4(0.f, 0.f, 0.f, 0.f);
    if (rv) {
      int k0 = kt + lk;
      const float* ap = (k0 < D_IN) ? (x + grow * D_IN + k0)
                                    : (agg + grow * (2 * D_IN) + (k0 - D_IN));
      av = *(const float4*)ap;
    }
    float4 bv[4];
    #pragma unroll
    for (int u = 0; u < 4; ++u) {
      int flat = u * 1024 + t * 4;
      int k = flat >> 8, j = flat & 255;
      int vk = kt + k;
      const float* bp = (vk < D_IN) ? (w1s + (long)vk * 256 + j)
                                    : (w1r + (long)(vk - D_IN) * 256 + j);
      bv[u] = *(const float4*)bp;
    }
    __syncthreads();
    As[lk + 0][lr] = av.x;
    As[lk + 1][lr] = av.y;
    As[lk + 2][lr] = av.z;
    As[lk + 3][lr] = av.w;
    #pragma unroll
    for (int u = 0; u < 4; ++u) {
      int flat = u * 1024 + t * 4;
      int k = flat >> 8, j = flat & 255;
      *(float4*)&Bs[k][j] = bv[u];
    }
    __syncthreads();
    #pragma unroll
    for (int k = 0; k < 16; ++k) {
      float a[8], b[8];
      #pragma unroll
      for (int m = 0; m < 8; ++m) a[m] = As[k][ty * 8 + m];
      #pragma unroll
      for (int n = 0; n < 8; ++n) b[n] = Bs[k][tx * 8 + n];
      #pragma unroll
      for (int m = 0; m < 8; ++m)
        #pragma unroll
        for (int n = 0; n < 8; ++n)
          acc[m][n] = fmaf(a[m], b[n], acc[m][n]);
    }
  }

  float zp[8][6];
  #pragma unroll
  for (int m = 0; m < 8; ++m)
    #pragma unroll
    for (int p = 0; p < 6; ++p) zp[m][p] = 0.f;

  #pragma unroll
  for (int n = 0; n < 8; ++n) {
    int col = tx * 8 + n;
    float bb = b1[col];
    float c0 = w2r[col * 2 + 0];
    float c1 = w2r[col * 2 + 1];
    float c2 = w2r[512 + col * 2 + 0];
    float c3 = w2r[512 + col * 2 + 1];
    float c4 = w2s[col * 2 + 0];
    float c5 = w2s[col * 2 + 1];
    #pragma unroll
    for (int m = 0; m < 8; ++m) {
      float h = acc[m][n] + bb;
      h = h > 0.f ? h : 0.f;
      zp[m][0] = fmaf(h, c0, zp[m][0]);
      zp[m][1] = fmaf(h, c1, zp[m][1]);
      zp[m][2] = fmaf(h, c2, zp[m][2]);
      zp[m][3] = fmaf(h, c3, zp[m][3]);
      zp[m][4] = fmaf(h, c4, zp[m][4]);
      zp[m][5] = fmaf(h, c5, zp[m][5]);
    }
  }
  #pragma unroll
  for (int m = 0; m < 8; ++m)
    #pragma unroll
    for (int p = 0; p < 6; ++p) {
      float v = zp[m][p];
      #pragma unroll
      for (int o = 16; o >= 1; o >>= 1) v += __shfl_xor(v, o, 32);
      zp[m][p] = v;
    }
  if (tx == 0) {
    float b20 = b2[0], b21 = b2[1];
    #pragma unroll
    for (int m = 0; m < 8; ++m) {
      long row = rowBase + ty * 8 + m;
      if (row < NN) {
        z2[row * 4 + 0] = zp[m][0];
        z2[row * 4 + 1] = zp[m][1];
        z2[row * 4 + 2] = zp[m][2];
        z2[row * 4 + 3] = zp[m][3];
        out[row * 2 + 0] = zp[m][4] + b20;
        out[row * 2 + 1] = zp[m][5] + b21;
      }
    }
  }
}

// one thread per node: sum z2 of in-neighbors per relation, add into out.
__global__ void gather2(const float* __restrict__ z2, const int* __restrict__ off,
                        const int* __restrict__ srcs, float* __restrict__ out) {
  int n = blockIdx.x * blockDim.x + threadIdx.x;
  if (n >= NN) return;
  int e0 = (n == 0) ? 0 : off[2 * n - 1];
  int e1 = off[2 * n];
  int e2 = off[2 * n + 1];
  float o0 = 0.f, o1 = 0.f;
  for (int e = e0; e < e1; ++e) {
    int s = srcs[e];
    float2 v = *(const float2*)(z2 + (long)s * 4);
    o0 += v.x; o1 += v.y;
  }
  for (int e = e1; e < e2; ++e) {
    int s = srcs[e];
    float2 v = *(const float2*)(z2 + (long)s * 4 + 2);
    o0 += v.x; o1 += v.y;
  }
  out[n * 2 + 0] += o0;
  out[n * 2 + 1] += o1;
}

// ---- R1 fallback kernels (used only if ws_size too small for CSR) ----
__global__ void scatter1(const float* __restrict__ x,
                         const int* __restrict__ src,
                         const int* __restrict__ dst,
                         const int* __restrict__ et,
                         float* __restrict__ agg, int E) {
  int tid = blockIdx.x * blockDim.x + threadIdx.x;
  int e = tid >> 5;
  if (e >= E) return;
  int c = tid & 31;
  int s = src[e], d = dst[e], r = et[e];
  float4 v = *(const float4*)(x + (long)s * D_IN + c * 4);
  float* a = agg + ((long)d * 2 + r) * D_IN + c * 4;
  unsafeAtomicAdd(a + 0, v.x);
  unsafeAtomicAdd(a + 1, v.y);
  unsafeAtomicAdd(a + 2, v.z);
  unsafeAtomicAdd(a + 3, v.w);
}

__global__ void scatter2(const float* __restrict__ z2,
                         const int* __restrict__ src,
                         const int* __restrict__ dst,
                         const int* __restrict__ et,
                         float* __restrict__ out, int E) {
  int e = blockIdx.x * blockDim.x + threadIdx.x;
  if (e >= E) return;
  int s = src[e], d = dst[e], r = et[e];
  float2 v = *(const float2*)(z2 + (long)s * 4 + r * 2);
  unsafeAtomicAdd(out + d * 2 + 0, v.x);
  unsafeAtomicAdd(out + d * 2 + 1, v.y);
}

extern "C" void kernel_launch(void* const* d_in, const int* in_sizes, int n_in,
                              void* d_out, int out_size, void* d_ws, size_t ws_size,
                              hipStream_t stream) {
  const float* x   = (const float*)d_in[0];
  const int*   ei  = (const int*)d_in[1];
  const int*   et  = (const int*)d_in[2];
  const float* w1s = (const float*)d_in[3];
  const float* w1r = (const float*)d_in[4];
  const float* b1  = (const float*)d_in[5];
  const float* w2s = (const float*)d_in[6];
  const float* w2r = (const float*)d_in[7];
  const float* b2  = (const float*)d_in[8];
  float* out = (float*)d_out;
  const int E = in_sizes[2];
  const int* src = ei;
  const int* dst = ei + E;

  float* agg = (float*)d_ws;                         // NN*256 f32  (102.4 MB)
  float* z2  = agg + (long)NN * 256;                 // NN*4 f32    (1.6 MB)
  int*   srcs = (int*)(z2 + (long)NN * 4);           // E ints      (6.4 MB)
  int*   off  = srcs + E;                            // NR ints     (0.8 MB)
  int*   partials = off + NR;                        // 1024 ints
  size_t need = (size_t)((long)NN * 256 + (long)NN * 4) * 4 +
                (size_t)(E + NR + 1024) * 4;

  if (ws_size >= need) {
    zero_i<<<SCAN_BLKS, 256, 0, stream>>>(off, NR);
    hist<<<(E + 255) / 256, 256, 0, stream>>>(dst, et, off, E);
    scan1<<<SCAN_BLKS, 256, 0, stream>>>(off, partials);
    scan2<<<1, 1024, 0, stream>>>(partials);
    scan3<<<SCAN_BLKS, 256, 0, stream>>>(off, partials);
    reorder<<<(E + 255) / 256, 256, 0, stream>>>(src, dst, et, off, srcs, E);
    aggregate<<<(NN * 64 + 255) / 256, 256, 0, stream>>>(x, off, srcs, agg);
    gemm1<<<(NN + 63) / 64, 256, 0, stream>>>(x, agg, w1s, w1r, b1, w2s, w2r, b2, z2, out);
    gather2<<<(NN + 255) / 256, 256, 0, stream>>>(z2, off, srcs, out);
  } else {
    int n4 = NN * 256 / 4;
    zero_f4<<<(n4 + 255) / 256, 256, 0, stream>>>((float4*)agg, n4);
    long thr1 = (long)E * 32;
    scatter1<<<(int)((thr1 + 255) / 256), 256, 0, stream>>>(x, src, dst, et, agg, E);
    gemm1<<<(NN + 63) / 64, 256, 0, stream>>>(x, agg, w1s, w1r, b1, w2s, w2r, b2, z2, out);
    scatter2<<<(E + 255) / 256, 256, 0, stream>>>(z2, src, dst, et, out, E);
  }
}

// Round 3
// 799.170 us; speedup vs baseline: 4.5659x; 1.4468x over previous
//
#include <hip/hip_runtime.h>

// HGIN_classifier: two relational-GIN layers (R=2), ReLU between.
// R3: add __launch_bounds__(256) to gemm1. R2's VGPR_Count=64 (default
// 1024-thread assumption) caused acc[8][8]+zp[8][6] to spill to scratch:
// FETCH 783MB / WRITE 1.63GB for a kernel with 155MB/2.4MB ideal traffic.
// Pipeline: zero_i -> hist -> scan1/2/3 -> reorder (CSR build, int atomics)
//           aggregate (gather, 1 wave/node) -> gemm1 (fused L1+L2 transform)
//           gather2 (CSR gather of z2 into out)

constexpr int NN   = 100000;
constexpr int D_IN = 128;
constexpr int NR   = NN * 2;                 // (node, relation) segments
constexpr int SCAN_BLKS = (NR + 255) / 256;  // 782

__global__ void zero_f4(float4* __restrict__ p, int n4) {
  int i = blockIdx.x * blockDim.x + threadIdx.x;
  if (i < n4) p[i] = make_float4(0.f, 0.f, 0.f, 0.f);
}

__global__ void zero_i(int* __restrict__ p, int n) {
  int i = blockIdx.x * blockDim.x + threadIdx.x;
  if (i < n) p[i] = 0;
}

__global__ void hist(const int* __restrict__ dst, const int* __restrict__ et,
                     int* __restrict__ cnt, int E) {
  int e = blockIdx.x * blockDim.x + threadIdx.x;
  if (e >= E) return;
  atomicAdd(&cnt[dst[e] * 2 + et[e]], 1);
}

// exclusive scan of cnt[NR] in place, block-level; partials[b] = block sum
__global__ void scan1(int* __restrict__ cnt, int* __restrict__ partials) {
  __shared__ int s[256];
  int tid = threadIdx.x;
  int i = blockIdx.x * 256 + tid;
  int v = (i < NR) ? cnt[i] : 0;
  s[tid] = v;
  __syncthreads();
  #pragma unroll
  for (int o = 1; o < 256; o <<= 1) {
    int t = (tid >= o) ? s[tid - o] : 0;
    __syncthreads();
    s[tid] += t;
    __syncthreads();
  }
  if (i < NR) cnt[i] = s[tid] - v;          // exclusive within block
  if (tid == 255) partials[blockIdx.x] = s[255];
}

__global__ void scan2(int* __restrict__ partials) {  // 1 block, 1024 threads
  __shared__ int s[1024];
  int tid = threadIdx.x;
  int v = (tid < SCAN_BLKS) ? partials[tid] : 0;
  s[tid] = v;
  __syncthreads();
  #pragma unroll
  for (int o = 1; o < 1024; o <<= 1) {
    int t = (tid >= o) ? s[tid - o] : 0;
    __syncthreads();
    s[tid] += t;
    __syncthreads();
  }
  partials[tid] = s[tid] - v;               // exclusive
}

__global__ void scan3(int* __restrict__ cnt, const int* __restrict__ partials) {
  int i = blockIdx.x * 256 + threadIdx.x;
  if (i < NR) cnt[i] += partials[blockIdx.x];
}

// After reorder, off[seg] == segment END; start = (seg==0) ? 0 : off[seg-1].
__global__ void reorder(const int* __restrict__ src, const int* __restrict__ dst,
                        const int* __restrict__ et, int* __restrict__ off,
                        int* __restrict__ srcs, int E) {
  int e = blockIdx.x * blockDim.x + threadIdx.x;
  if (e >= E) return;
  int seg = dst[e] * 2 + et[e];
  int p = atomicAdd(&off[seg], 1);
  srcs[p] = src[e];
}

// One wave (64 lanes) per node; lane l accumulates columns [2l, 2l+1].
__global__ void aggregate(const float* __restrict__ x, const int* __restrict__ off,
                          const int* __restrict__ srcs, float* __restrict__ agg) {
  int w = (blockIdx.x * blockDim.x + threadIdx.x) >> 6;
  if (w >= NN) return;
  int lane = threadIdx.x & 63;
  int e0 = (w == 0) ? 0 : off[2 * w - 1];
  int e1 = off[2 * w];
  int e2 = off[2 * w + 1];
  float2 a0 = make_float2(0.f, 0.f), a1 = make_float2(0.f, 0.f);
  for (int e = e0; e < e1; ++e) {
    int s = srcs[e];
    float2 v = *(const float2*)(x + (long)s * D_IN + lane * 2);
    a0.x += v.x; a0.y += v.y;
  }
  for (int e = e1; e < e2; ++e) {
    int s = srcs[e];
    float2 v = *(const float2*)(x + (long)s * D_IN + lane * 2);
    a1.x += v.x; a1.y += v.y;
  }
  float* row = agg + (long)w * 256;
  *(float2*)(row + lane * 2) = a0;
  *(float2*)(row + 128 + lane * 2) = a1;
}

// ---- layer-1 GEMM + fused layer-2 transform ----
// Virtual A[i][k]: k<128 -> x[i*128+k], else agg[i*256+(k-128)]
// Virtual W[k][j]: k<128 -> w1s[k*256+j], else w1r[(k-128)*256+j]
__global__ __launch_bounds__(256) void gemm1(
                      const float* __restrict__ x,
                      const float* __restrict__ agg,
                      const float* __restrict__ w1s,
                      const float* __restrict__ w1r,
                      const float* __restrict__ b1,
                      const float* __restrict__ w2s,
                      const float* __restrict__ w2r,
                      const float* __restrict__ b2,
                      float* __restrict__ z2,
                      float* __restrict__ out) {
  __shared__ float As[16][64];
  __shared__ float Bs[16][256];
  const int t = threadIdx.x;
  const int tx = t & 31, ty = t >> 5;
  const long rowBase = (long)blockIdx.x * 64;
  const int lr = t >> 2;
  const int lk = (t & 3) * 4;
  const long grow = rowBase + lr;
  const bool rv = grow < NN;

  float acc[8][8];
  #pragma unroll
  for (int m = 0; m < 8; ++m)
    #pragma unroll
    for (int n = 0; n < 8; ++n) acc[m][n] = 0.f;

  for (int kt = 0; kt < 384; kt += 16) {
    float4 av = make_float4(0.f, 0.f, 0.f, 0.f);
    if (rv) {
      int k0 = kt + lk;
      const float* ap = (k0 < D_IN) ? (x + grow * D_IN + k0)
                                    : (agg + grow * (2 * D_IN) + (k0 - D_IN));
      av = *(const float4*)ap;
    }
    float4 bv[4];
    #pragma unroll
    for (int u = 0; u < 4; ++u) {
      int flat = u * 1024 + t * 4;
      int k = flat >> 8, j = flat & 255;
      int vk = kt + k;
      const float* bp = (vk < D_IN) ? (w1s + (long)vk * 256 + j)
                                    : (w1r + (long)(vk - D_IN) * 256 + j);
      bv[u] = *(const float4*)bp;
    }
    __syncthreads();
    As[lk + 0][lr] = av.x;
    As[lk + 1][lr] = av.y;
    As[lk + 2][lr] = av.z;
    As[lk + 3][lr] = av.w;
    #pragma unroll
    for (int u = 0; u < 4; ++u) {
      int flat = u * 1024 + t * 4;
      int k = flat >> 8, j = flat & 255;
      *(float4*)&Bs[k][j] = bv[u];
    }
    __syncthreads();
    #pragma unroll
    for (int k = 0; k < 16; ++k) {
      float a[8], b[8];
      #pragma unroll
      for (int m = 0; m < 8; ++m) a[m] = As[k][ty * 8 + m];
      #pragma unroll
      for (int n = 0; n < 8; ++n) b[n] = Bs[k][tx * 8 + n];
      #pragma unroll
      for (int m = 0; m < 8; ++m)
        #pragma unroll
        for (int n = 0; n < 8; ++n)
          acc[m][n] = fmaf(a[m], b[n], acc[m][n]);
    }
  }

  float zp[8][6];
  #pragma unroll
  for (int m = 0; m < 8; ++m)
    #pragma unroll
    for (int p = 0; p < 6; ++p) zp[m][p] = 0.f;

  #pragma unroll
  for (int n = 0; n < 8; ++n) {
    int col = tx * 8 + n;
    float bb = b1[col];
    float c0 = w2r[col * 2 + 0];
    float c1 = w2r[col * 2 + 1];
    float c2 = w2r[512 + col * 2 + 0];
    float c3 = w2r[512 + col * 2 + 1];
    float c4 = w2s[col * 2 + 0];
    float c5 = w2s[col * 2 + 1];
    #pragma unroll
    for (int m = 0; m < 8; ++m) {
      float h = acc[m][n] + bb;
      h = h > 0.f ? h : 0.f;
      zp[m][0] = fmaf(h, c0, zp[m][0]);
      zp[m][1] = fmaf(h, c1, zp[m][1]);
      zp[m][2] = fmaf(h, c2, zp[m][2]);
      zp[m][3] = fmaf(h, c3, zp[m][3]);
      zp[m][4] = fmaf(h, c4, zp[m][4]);
      zp[m][5] = fmaf(h, c5, zp[m][5]);
    }
  }
  #pragma unroll
  for (int m = 0; m < 8; ++m)
    #pragma unroll
    for (int p = 0; p < 6; ++p) {
      float v = zp[m][p];
      #pragma unroll
      for (int o = 16; o >= 1; o >>= 1) v += __shfl_xor(v, o, 32);
      zp[m][p] = v;
    }
  if (tx == 0) {
    float b20 = b2[0], b21 = b2[1];
    #pragma unroll
    for (int m = 0; m < 8; ++m) {
      long row = rowBase + ty * 8 + m;
      if (row < NN) {
        z2[row * 4 + 0] = zp[m][0];
        z2[row * 4 + 1] = zp[m][1];
        z2[row * 4 + 2] = zp[m][2];
        z2[row * 4 + 3] = zp[m][3];
        out[row * 2 + 0] = zp[m][4] + b20;
        out[row * 2 + 1] = zp[m][5] + b21;
      }
    }
  }
}

// one thread per node: sum z2 of in-neighbors per relation, add into out.
__global__ void gather2(const float* __restrict__ z2, const int* __restrict__ off,
                        const int* __restrict__ srcs, float* __restrict__ out) {
  int n = blockIdx.x * blockDim.x + threadIdx.x;
  if (n >= NN) return;
  int e0 = (n == 0) ? 0 : off[2 * n - 1];
  int e1 = off[2 * n];
  int e2 = off[2 * n + 1];
  float o0 = 0.f, o1 = 0.f;
  for (int e = e0; e < e1; ++e) {
    int s = srcs[e];
    float2 v = *(const float2*)(z2 + (long)s * 4);
    o0 += v.x; o1 += v.y;
  }
  for (int e = e1; e < e2; ++e) {
    int s = srcs[e];
    float2 v = *(const float2*)(z2 + (long)s * 4 + 2);
    o0 += v.x; o1 += v.y;
  }
  out[n * 2 + 0] += o0;
  out[n * 2 + 1] += o1;
}

// ---- R1 fallback kernels (used only if ws_size too small for CSR) ----
__global__ void scatter1(const float* __restrict__ x,
                         const int* __restrict__ src,
                         const int* __restrict__ dst,
                         const int* __restrict__ et,
                         float* __restrict__ agg, int E) {
  int tid = blockIdx.x * blockDim.x + threadIdx.x;
  int e = tid >> 5;
  if (e >= E) return;
  int c = tid & 31;
  int s = src[e], d = dst[e], r = et[e];
  float4 v = *(const float4*)(x + (long)s * D_IN + c * 4);
  float* a = agg + ((long)d * 2 + r) * D_IN + c * 4;
  unsafeAtomicAdd(a + 0, v.x);
  unsafeAtomicAdd(a + 1, v.y);
  unsafeAtomicAdd(a + 2, v.z);
  unsafeAtomicAdd(a + 3, v.w);
}

__global__ void scatter2(const float* __restrict__ z2,
                         const int* __restrict__ src,
                         const int* __restrict__ dst,
                         const int* __restrict__ et,
                         float* __restrict__ out, int E) {
  int e = blockIdx.x * blockDim.x + threadIdx.x;
  if (e >= E) return;
  int s = src[e], d = dst[e], r = et[e];
  float2 v = *(const float2*)(z2 + (long)s * 4 + r * 2);
  unsafeAtomicAdd(out + d * 2 + 0, v.x);
  unsafeAtomicAdd(out + d * 2 + 1, v.y);
}

extern "C" void kernel_launch(void* const* d_in, const int* in_sizes, int n_in,
                              void* d_out, int out_size, void* d_ws, size_t ws_size,
                              hipStream_t stream) {
  const float* x   = (const float*)d_in[0];
  const int*   ei  = (const int*)d_in[1];
  const int*   et  = (const int*)d_in[2];
  const float* w1s = (const float*)d_in[3];
  const float* w1r = (const float*)d_in[4];
  const float* b1  = (const float*)d_in[5];
  const float* w2s = (const float*)d_in[6];
  const float* w2r = (const float*)d_in[7];
  const float* b2  = (const float*)d_in[8];
  float* out = (float*)d_out;
  const int E = in_sizes[2];
  const int* src = ei;
  const int* dst = ei + E;

  float* agg = (float*)d_ws;                         // NN*256 f32  (102.4 MB)
  float* z2  = agg + (long)NN * 256;                 // NN*4 f32    (1.6 MB)
  int*   srcs = (int*)(z2 + (long)NN * 4);           // E ints      (6.4 MB)
  int*   off  = srcs + E;                            // NR ints     (0.8 MB)
  int*   partials = off + NR;                        // 1024 ints
  size_t need = (size_t)((long)NN * 256 + (long)NN * 4) * 4 +
                (size_t)(E + NR + 1024) * 4;

  if (ws_size >= need) {
    zero_i<<<SCAN_BLKS, 256, 0, stream>>>(off, NR);
    hist<<<(E + 255) / 256, 256, 0, stream>>>(dst, et, off, E);
    scan1<<<SCAN_BLKS, 256, 0, stream>>>(off, partials);
    scan2<<<1, 1024, 0, stream>>>(partials);
    scan3<<<SCAN_BLKS, 256, 0, stream>>>(off, partials);
    reorder<<<(E + 255) / 256, 256, 0, stream>>>(src, dst, et, off, srcs, E);
    aggregate<<<(NN * 64 + 255) / 256, 256, 0, stream>>>(x, off, srcs, agg);
    gemm1<<<(NN + 63) / 64, 256, 0, stream>>>(x, agg, w1s, w1r, b1, w2s, w2r, b2, z2, out);
    gather2<<<(NN + 255) / 256, 256, 0, stream>>>(z2, off, srcs, out);
  } else {
    int n4 = NN * 256 / 4;
    zero_f4<<<(n4 + 255) / 256, 256, 0, stream>>>((float4*)agg, n4);
    long thr1 = (long)E * 32;
    scatter1<<<(int)((thr1 + 255) / 256), 256, 0, stream>>>(x, src, dst, et, agg, E);
    gemm1<<<(NN + 63) / 64, 256, 0, stream>>>(x, agg, w1s, w1r, b1, w2s, w2r, b2, z2, out);
    scatter2<<<(E + 255) / 256, 256, 0, stream>>>(z2, src, dst, et, out, E);
  }
}

// Round 4
// 606.605 us; speedup vs baseline: 6.0153x; 1.3174x over previous
//
#include <hip/hip_runtime.h>

// HGIN_classifier: two relational-GIN layers (R=2), ReLU between.
// R4: f16 MFMA for the fused layer-1 GEMM (fp32 vector floor was 125us;
// R3 measured 366us, LDS-scalar-read + epilogue-spill bound). x and agg are
// converted to f16 (err ~0.02 << 1.105 threshold); W1 pre-transposed to f16.
// aggregate now gathers f16 x rows (halves its traffic).
// Pipeline: zero_i -> hist -> scan1/2/3 -> reorder (CSR build)
//           cvt_x, cvt_w -> aggregate (f16 gather) -> gemm_mfma -> gather2

typedef _Float16 f16;
typedef _Float16 f16x2 __attribute__((ext_vector_type(2)));
typedef _Float16 f16x4 __attribute__((ext_vector_type(4)));
typedef _Float16 f16x8 __attribute__((ext_vector_type(8)));
typedef float    f32x4 __attribute__((ext_vector_type(4)));

constexpr int NN   = 100000;
constexpr int NR   = NN * 2;
constexpr int SCAN_BLKS = (NR + 255) / 256;  // 782

__global__ void zero_i(int* __restrict__ p, int n) {
  int i = blockIdx.x * blockDim.x + threadIdx.x;
  if (i < n) p[i] = 0;
}

__global__ void hist(const int* __restrict__ dst, const int* __restrict__ et,
                     int* __restrict__ cnt, int E) {
  int e = blockIdx.x * blockDim.x + threadIdx.x;
  if (e >= E) return;
  atomicAdd(&cnt[dst[e] * 2 + et[e]], 1);
}

__global__ void scan1(int* __restrict__ cnt, int* __restrict__ partials) {
  __shared__ int s[256];
  int tid = threadIdx.x;
  int i = blockIdx.x * 256 + tid;
  int v = (i < NR) ? cnt[i] : 0;
  s[tid] = v;
  __syncthreads();
  #pragma unroll
  for (int o = 1; o < 256; o <<= 1) {
    int t = (tid >= o) ? s[tid - o] : 0;
    __syncthreads();
    s[tid] += t;
    __syncthreads();
  }
  if (i < NR) cnt[i] = s[tid] - v;
  if (tid == 255) partials[blockIdx.x] = s[255];
}

__global__ void scan2(int* __restrict__ partials) {
  __shared__ int s[1024];
  int tid = threadIdx.x;
  int v = (tid < SCAN_BLKS) ? partials[tid] : 0;
  s[tid] = v;
  __syncthreads();
  #pragma unroll
  for (int o = 1; o < 1024; o <<= 1) {
    int t = (tid >= o) ? s[tid - o] : 0;
    __syncthreads();
    s[tid] += t;
    __syncthreads();
  }
  partials[tid] = s[tid] - v;
}

__global__ void scan3(int* __restrict__ cnt, const int* __restrict__ partials) {
  int i = blockIdx.x * 256 + threadIdx.x;
  if (i < NR) cnt[i] += partials[blockIdx.x];
}

// After reorder, off[seg] == segment END; start = (seg==0) ? 0 : off[seg-1].
__global__ void reorder(const int* __restrict__ src, const int* __restrict__ dst,
                        const int* __restrict__ et, int* __restrict__ off,
                        int* __restrict__ srcs, int E) {
  int e = blockIdx.x * blockDim.x + threadIdx.x;
  if (e >= E) return;
  int seg = dst[e] * 2 + et[e];
  int p = atomicAdd(&off[seg], 1);
  srcs[p] = src[e];
}

__global__ void cvt_x(const float4* __restrict__ xf, f16* __restrict__ xh, int n4) {
  int i = blockIdx.x * blockDim.x + threadIdx.x;
  if (i >= n4) return;
  float4 v = xf[i];
  f16x4 h;
  h.x = (f16)v.x; h.y = (f16)v.y; h.z = (f16)v.z; h.w = (f16)v.w;
  *(f16x4*)(xh + (size_t)i * 4) = h;
}

// w1t[n][k] = f16( W[k][n] ), k in [0,384): k<128 -> w1s, else w1r (flat).
__global__ void cvt_w(const float* __restrict__ w1s, const float* __restrict__ w1r,
                      f16* __restrict__ w1t) {
  int id = blockIdx.x * blockDim.x + threadIdx.x;
  if (id >= 384 * 256) return;
  int k = id >> 8, n = id & 255;
  float v = (k < 128) ? w1s[k * 256 + n] : w1r[(k - 128) * 256 + n];
  w1t[n * 384 + k] = (f16)v;
}

// One wave per node; lane l owns cols 2l,2l+1; gathers f16 x rows (256 B each).
__global__ void aggregate(const f16* __restrict__ xh, const int* __restrict__ off,
                          const int* __restrict__ srcs, f16* __restrict__ aggh) {
  int w = (blockIdx.x * blockDim.x + threadIdx.x) >> 6;
  if (w >= NN) return;
  int lane = threadIdx.x & 63;
  int e0 = (w == 0) ? 0 : off[2 * w - 1];
  int e1 = off[2 * w];
  int e2 = off[2 * w + 1];
  float a0 = 0.f, a1 = 0.f, c0 = 0.f, c1 = 0.f;
  for (int e = e0; e < e1; ++e) {
    f16x2 v = *(const f16x2*)(xh + (long)srcs[e] * 128 + lane * 2);
    a0 += (float)v.x; a1 += (float)v.y;
  }
  for (int e = e1; e < e2; ++e) {
    f16x2 v = *(const f16x2*)(xh + (long)srcs[e] * 128 + lane * 2);
    c0 += (float)v.x; c1 += (float)v.y;
  }
  f16* row = aggh + (long)w * 256;
  f16x2 o0; o0.x = (f16)a0; o0.y = (f16)a1;
  f16x2 o1; o1.x = (f16)c0; o1.y = (f16)c1;
  *(f16x2*)(row + lane * 2) = o0;
  *(f16x2*)(row + 128 + lane * 2) = o1;
}

// Fused layer-1 GEMM (f16 MFMA, fp32 acc) + layer-2 transform epilogue.
// Block: 256 thr = 4 waves; tile 64 rows x 256 cols.
// Wave wv: rg=wv>>1 -> rows rg*32..+31 (2 m-tiles), cg=wv&1 -> cols cg*128..+127 (8 n-tiles).
// Virtual A[i][k]: k<128 -> xh[i][k], else aggh[i][k-128].  B[k][n] = w1t[n][k].
// Fragment layouts (m89/m120-verified): A: m=lane&15, k=quad*8+j; B: n=lane&15,
// k=quad*8+j; C/D: col=lane&15, row=quad*4+reg.
__global__ __launch_bounds__(256) void gemm_mfma(
    const f16* __restrict__ xh, const f16* __restrict__ aggh,
    const f16* __restrict__ w1t,
    const float* __restrict__ b1, const float* __restrict__ w2s,
    const float* __restrict__ w2r, const float* __restrict__ b2,
    float* __restrict__ z2, float* __restrict__ out) {
  __shared__ __align__(16) f16 Ash[64 * 40];    // rows padded to 40 halfs (80 B)
  __shared__ __align__(16) f16 Bsh[256 * 40];
  __shared__ float zbuf[2][64][6];
  const int t = threadIdx.x;
  const long rowBase = (long)blockIdx.x * 64;
  const int sr = t >> 2, sc = t & 3;            // A staging: row, 16B-chunk
  const long arow = rowBase + sr;
  const bool arv = arow < NN;
  const int lane = t & 63, wv = t >> 6;
  const int rg = wv >> 1, cg = wv & 1;
  const int ml = lane & 15, quad = lane >> 4;

  f32x4 acc[2][8];
  #pragma unroll
  for (int mt = 0; mt < 2; ++mt)
    #pragma unroll
    for (int nt = 0; nt < 8; ++nt)
      acc[mt][nt] = (f32x4)(0.f);

  for (int ks = 0; ks < 12; ++ks) {
    const int kt = ks * 32;
    uint4 av = make_uint4(0, 0, 0, 0);
    if (arv) {
      const f16* ap = (kt < 128) ? (xh + arow * 128 + kt + sc * 8)
                                 : (aggh + arow * 256 + (kt - 128) + sc * 8);
      av = *(const uint4*)ap;
    }
    uint4 bv[4];
    {
      const uint4* bp = (const uint4*)(w1t + (long)t * 384 + kt);
      #pragma unroll
      for (int c = 0; c < 4; ++c) bv[c] = bp[c];
    }
    __syncthreads();
    *(uint4*)&Ash[sr * 40 + sc * 8] = av;
    #pragma unroll
    for (int c = 0; c < 4; ++c) *(uint4*)&Bsh[t * 40 + c * 8] = bv[c];
    __syncthreads();

    f16x8 af[2], bf[8];
    #pragma unroll
    for (int mt = 0; mt < 2; ++mt)
      af[mt] = *(const f16x8*)&Ash[(rg * 32 + mt * 16 + ml) * 40 + quad * 8];
    #pragma unroll
    for (int nt = 0; nt < 8; ++nt)
      bf[nt] = *(const f16x8*)&Bsh[(cg * 128 + nt * 16 + ml) * 40 + quad * 8];
    #pragma unroll
    for (int mt = 0; mt < 2; ++mt)
      #pragma unroll
      for (int nt = 0; nt < 8; ++nt)
        acc[mt][nt] = __builtin_amdgcn_mfma_f32_16x16x32_f16(af[mt], bf[nt],
                                                             acc[mt][nt], 0, 0, 0);
  }

  // Epilogue: h = relu(acc + b1[col]); 6 dots over cols; reduce 16 lanes/quad.
  #pragma unroll
  for (int mt = 0; mt < 2; ++mt) {
    float z[4][6];
    #pragma unroll
    for (int rr = 0; rr < 4; ++rr)
      #pragma unroll
      for (int p = 0; p < 6; ++p) z[rr][p] = 0.f;
    #pragma unroll
    for (int nt = 0; nt < 8; ++nt) {
      int col = cg * 128 + nt * 16 + ml;
      float bb = b1[col];
      float wA = w2r[col * 2 + 0];
      float wB = w2r[col * 2 + 1];
      float wC = w2r[512 + col * 2 + 0];
      float wD = w2r[512 + col * 2 + 1];
      float wE = w2s[col * 2 + 0];
      float wF = w2s[col * 2 + 1];
      #pragma unroll
      for (int rr = 0; rr < 4; ++rr) {
        float h = acc[mt][nt][rr] + bb;
        h = h > 0.f ? h : 0.f;
        z[rr][0] = fmaf(h, wA, z[rr][0]);
        z[rr][1] = fmaf(h, wB, z[rr][1]);
        z[rr][2] = fmaf(h, wC, z[rr][2]);
        z[rr][3] = fmaf(h, wD, z[rr][3]);
        z[rr][4] = fmaf(h, wE, z[rr][4]);
        z[rr][5] = fmaf(h, wF, z[rr][5]);
      }
    }
    #pragma unroll
    for (int rr = 0; rr < 4; ++rr)
      #pragma unroll
      for (int p = 0; p < 6; ++p) {
        float v = z[rr][p];
        v += __shfl_xor(v, 1);
        v += __shfl_xor(v, 2);
        v += __shfl_xor(v, 4);
        v += __shfl_xor(v, 8);
        if (ml == 0) zbuf[cg][rg * 32 + mt * 16 + quad * 4 + rr][p] = v;
      }
  }
  __syncthreads();
  for (int i = t; i < 384; i += 256) {
    int r = i / 6, p = i % 6;
    long grow = rowBase + r;
    if (grow < NN) {
      float v = zbuf[0][r][p] + zbuf[1][r][p];
      if (p < 4) z2[grow * 4 + p] = v;
      else       out[grow * 2 + (p - 4)] = v + b2[p - 4];
    }
  }
}

// one thread per node: sum z2 of in-neighbors per relation, add into out.
__global__ void gather2(const float* __restrict__ z2, const int* __restrict__ off,
                        const int* __restrict__ srcs, float* __restrict__ out) {
  int n = blockIdx.x * blockDim.x + threadIdx.x;
  if (n >= NN) return;
  int e0 = (n == 0) ? 0 : off[2 * n - 1];
  int e1 = off[2 * n];
  int e2 = off[2 * n + 1];
  float o0 = 0.f, o1 = 0.f;
  for (int e = e0; e < e1; ++e) {
    float2 v = *(const float2*)(z2 + (long)srcs[e] * 4);
    o0 += v.x; o1 += v.y;
  }
  for (int e = e1; e < e2; ++e) {
    float2 v = *(const float2*)(z2 + (long)srcs[e] * 4 + 2);
    o0 += v.x; o1 += v.y;
  }
  out[n * 2 + 0] += o0;
  out[n * 2 + 1] += o1;
}

extern "C" void kernel_launch(void* const* d_in, const int* in_sizes, int n_in,
                              void* d_out, int out_size, void* d_ws, size_t ws_size,
                              hipStream_t stream) {
  const float* x   = (const float*)d_in[0];
  const int*   ei  = (const int*)d_in[1];
  const int*   et  = (const int*)d_in[2];
  const float* w1s = (const float*)d_in[3];
  const float* w1r = (const float*)d_in[4];
  const float* b1  = (const float*)d_in[5];
  const float* w2s = (const float*)d_in[6];
  const float* w2r = (const float*)d_in[7];
  const float* b2  = (const float*)d_in[8];
  float* out = (float*)d_out;
  const int E = in_sizes[2];
  const int* src = ei;
  const int* dst = ei + E;

  f16*   aggh = (f16*)d_ws;                    // NN*256 f16  (51.2 MB)
  f16*   xh   = aggh + (size_t)NN * 256;       // NN*128 f16  (25.6 MB)
  f16*   w1t  = xh + (size_t)NN * 128;         // 256*384 f16 (0.2 MB)
  float* z2   = (float*)(w1t + 256 * 384);     // NN*4 f32    (1.6 MB)
  int*   srcs = (int*)(z2 + (size_t)NN * 4);   // E ints      (6.4 MB)
  int*   off  = srcs + E;                      // NR ints     (0.8 MB)
  int*   partials = off + NR;                  // 1024 ints

  zero_i<<<SCAN_BLKS, 256, 0, stream>>>(off, NR);
  hist<<<(E + 255) / 256, 256, 0, stream>>>(dst, et, off, E);
  scan1<<<SCAN_BLKS, 256, 0, stream>>>(off, partials);
  scan2<<<1, 1024, 0, stream>>>(partials);
  scan3<<<SCAN_BLKS, 256, 0, stream>>>(off, partials);
  reorder<<<(E + 255) / 256, 256, 0, stream>>>(src, dst, et, off, srcs, E);

  int n4 = NN * 128 / 4;
  cvt_x<<<(n4 + 255) / 256, 256, 0, stream>>>((const float4*)x, xh, n4);
  cvt_w<<<(384 * 256 + 255) / 256, 256, 0, stream>>>(w1s, w1r, w1t);

  aggregate<<<(NN * 64 + 255) / 256, 256, 0, stream>>>(xh, off, srcs, aggh);

  gemm_mfma<<<(NN + 63) / 64, 256, 0, stream>>>(xh, aggh, w1t, b1, w2s, w2r, b2,
                                                z2, out);

  gather2<<<(NN + 255) / 256, 256, 0, stream>>>(z2, off, srcs, out);
}

// Round 5
// 499.806 us; speedup vs baseline: 7.3007x; 1.2137x over previous
//
#include <hip/hip_runtime.h>

// HGIN_classifier: two relational-GIN layers (R=2), ReLU between.
// R5: gemm restructured — 128x256 tile, LDS double-buffer + register prefetch
// (single barrier/iter, global latency overlapped with MFMA), W1 repacked
// k-step-major so B staging is contiguous/coalesced. gather2 4 lanes/node.
// Pipeline: zero_i -> hist -> scan1/2/3 -> reorder (CSR build)
//           cvt_x, cvt_w -> aggregate (f16 gather) -> gemm_mfma -> gather2

typedef _Float16 f16;
typedef _Float16 f16x2 __attribute__((ext_vector_type(2)));
typedef _Float16 f16x4 __attribute__((ext_vector_type(4)));
typedef _Float16 f16x8 __attribute__((ext_vector_type(8)));
typedef float    f32x4 __attribute__((ext_vector_type(4)));

constexpr int NN   = 100000;
constexpr int NR   = NN * 2;
constexpr int SCAN_BLKS = (NR + 255) / 256;  // 782

__global__ void zero_i(int* __restrict__ p, int n) {
  int i = blockIdx.x * blockDim.x + threadIdx.x;
  if (i < n) p[i] = 0;
}

__global__ void hist(const int* __restrict__ dst, const int* __restrict__ et,
                     int* __restrict__ cnt, int E) {
  int e = blockIdx.x * blockDim.x + threadIdx.x;
  if (e >= E) return;
  atomicAdd(&cnt[dst[e] * 2 + et[e]], 1);
}

__global__ void scan1(int* __restrict__ cnt, int* __restrict__ partials) {
  __shared__ int s[256];
  int tid = threadIdx.x;
  int i = blockIdx.x * 256 + tid;
  int v = (i < NR) ? cnt[i] : 0;
  s[tid] = v;
  __syncthreads();
  #pragma unroll
  for (int o = 1; o < 256; o <<= 1) {
    int t = (tid >= o) ? s[tid - o] : 0;
    __syncthreads();
    s[tid] += t;
    __syncthreads();
  }
  if (i < NR) cnt[i] = s[tid] - v;
  if (tid == 255) partials[blockIdx.x] = s[255];
}

__global__ void scan2(int* __restrict__ partials) {
  __shared__ int s[1024];
  int tid = threadIdx.x;
  int v = (tid < SCAN_BLKS) ? partials[tid] : 0;
  s[tid] = v;
  __syncthreads();
  #pragma unroll
  for (int o = 1; o < 1024; o <<= 1) {
    int t = (tid >= o) ? s[tid - o] : 0;
    __syncthreads();
    s[tid] += t;
    __syncthreads();
  }
  partials[tid] = s[tid] - v;
}

__global__ void scan3(int* __restrict__ cnt, const int* __restrict__ partials) {
  int i = blockIdx.x * 256 + threadIdx.x;
  if (i < NR) cnt[i] += partials[blockIdx.x];
}

// After reorder, off[seg] == segment END; start = (seg==0) ? 0 : off[seg-1].
__global__ void reorder(const int* __restrict__ src, const int* __restrict__ dst,
                        const int* __restrict__ et, int* __restrict__ off,
                        int* __restrict__ srcs, int E) {
  int e = blockIdx.x * blockDim.x + threadIdx.x;
  if (e >= E) return;
  int seg = dst[e] * 2 + et[e];
  int p = atomicAdd(&off[seg], 1);
  srcs[p] = src[e];
}

__global__ void cvt_x(const float4* __restrict__ xf, f16* __restrict__ xh, int n4) {
  int i = blockIdx.x * blockDim.x + threadIdx.x;
  if (i >= n4) return;
  float4 v = xf[i];
  f16x4 h;
  h.x = (f16)v.x; h.y = (f16)v.y; h.z = (f16)v.z; h.w = (f16)v.w;
  *(f16x4*)(xh + (size_t)i * 4) = h;
}

// k-step-major repack: w1t[ks][n][ki] = f16(W[ks*32+ki][n]); slab ks is a
// contiguous 16 KB block -> perfectly coalesced B staging in gemm.
__global__ void cvt_w(const float* __restrict__ w1s, const float* __restrict__ w1r,
                      f16* __restrict__ w1t) {
  int id = blockIdx.x * blockDim.x + threadIdx.x;
  if (id >= 12 * 256 * 32) return;
  int ks = id >> 13, rem = id & 8191;
  int n = rem >> 5, ki = rem & 31;
  int k = ks * 32 + ki;
  float v = (k < 128) ? w1s[k * 256 + n] : w1r[(k - 128) * 256 + n];
  w1t[id] = (f16)v;
}

// One wave per node; lane l owns cols 2l,2l+1; unroll x2 for outstanding loads.
__global__ void aggregate(const f16* __restrict__ xh, const int* __restrict__ off,
                          const int* __restrict__ srcs, f16* __restrict__ aggh) {
  int w = (blockIdx.x * blockDim.x + threadIdx.x) >> 6;
  if (w >= NN) return;
  int lane = threadIdx.x & 63;
  int e0 = (w == 0) ? 0 : off[2 * w - 1];
  int e1 = off[2 * w];
  int e2 = off[2 * w + 1];
  float a0 = 0.f, a1 = 0.f, c0 = 0.f, c1 = 0.f;
  int e = e0;
  for (; e + 1 < e1; e += 2) {
    f16x2 v0 = *(const f16x2*)(xh + (long)srcs[e] * 128 + lane * 2);
    f16x2 v1 = *(const f16x2*)(xh + (long)srcs[e + 1] * 128 + lane * 2);
    a0 += (float)v0.x + (float)v1.x;
    a1 += (float)v0.y + (float)v1.y;
  }
  if (e < e1) {
    f16x2 v = *(const f16x2*)(xh + (long)srcs[e] * 128 + lane * 2);
    a0 += (float)v.x; a1 += (float)v.y;
  }
  e = e1;
  for (; e + 1 < e2; e += 2) {
    f16x2 v0 = *(const f16x2*)(xh + (long)srcs[e] * 128 + lane * 2);
    f16x2 v1 = *(const f16x2*)(xh + (long)srcs[e + 1] * 128 + lane * 2);
    c0 += (float)v0.x + (float)v1.x;
    c1 += (float)v0.y + (float)v1.y;
  }
  if (e < e2) {
    f16x2 v = *(const f16x2*)(xh + (long)srcs[e] * 128 + lane * 2);
    c0 += (float)v.x; c1 += (float)v.y;
  }
  f16* row = aggh + (long)w * 256;
  f16x2 o0; o0.x = (f16)a0; o0.y = (f16)a1;
  f16x2 o1; o1.x = (f16)c0; o1.y = (f16)c1;
  *(f16x2*)(row + lane * 2) = o0;
  *(f16x2*)(row + 128 + lane * 2) = o1;
}

// Fused layer-1 GEMM (f16 MFMA) + layer-2 transform epilogue.
// 128 rows x 256 cols per block; 4 waves, wave = 64 rows x 128 cols
// (4 mt x 8 nt, acc = 128 VGPR). LDS double-buffered, register prefetch:
// tile ks+1 global loads issue before MFMA of ks; ONE barrier per iter.
// Fragment layouts (m89/m120-verified): A: m=lane&15, k=quad*8+j;
// B: n=lane&15, k=quad*8+j; C/D: col=lane&15, row=quad*4+reg.
__global__ __launch_bounds__(256, 2) void gemm_mfma(
    const f16* __restrict__ xh, const f16* __restrict__ aggh,
    const f16* __restrict__ w1t,
    const float* __restrict__ b1, const float* __restrict__ w2s,
    const float* __restrict__ w2r, const float* __restrict__ b2,
    float* __restrict__ z2, float* __restrict__ out) {
  __shared__ __align__(16) f16 Ash[2][128 * 40];   // 10 KB each
  __shared__ __align__(16) f16 Bsh[2][256 * 40];   // 20 KB each
  __shared__ float zbuf[2][128][6];                // 6 KB
  const int t = threadIdx.x;
  const long rowBase = (long)blockIdx.x * 128;
  const int lane = t & 63, wv = t >> 6;
  const int rg = wv >> 1, cg = wv & 1;
  const int ml = lane & 15, quad = lane >> 4;

  // staging maps (2-way-max LDS write aliasing):
  // A: g = c*256+t (c=0,1): row=g>>2, chunk=g&3  -> 128 rows x 4 chunks
  // B: g = c*256+t (c=0..3): n=g>>2, chunk=g&3   -> contiguous global reads
  f32x4 acc[4][8];
  #pragma unroll
  for (int mt = 0; mt < 4; ++mt)
    #pragma unroll
    for (int nt = 0; nt < 8; ++nt) acc[mt][nt] = (f32x4)(0.f);

  uint4 av[2], bv[4];
  auto load_tile = [&](int ks) {
    const int kt = ks * 32;
    #pragma unroll
    for (int c = 0; c < 2; ++c) {
      int g = c * 256 + t;
      int r = g >> 2, ch = g & 3;
      long grow = rowBase + r;
      if (grow < NN) {
        int k0 = kt + ch * 8;
        const f16* ap = (kt < 128) ? (xh + grow * 128 + k0)
                                   : (aggh + grow * 256 + (k0 - 128));
        av[c] = *(const uint4*)ap;
      } else {
        av[c] = make_uint4(0, 0, 0, 0);
      }
    }
    const uint4* bp = (const uint4*)(w1t + (long)ks * 8192) + t;
    #pragma unroll
    for (int c = 0; c < 4; ++c) bv[c] = bp[c * 256];
  };
  auto store_tile = [&](int buf) {
    #pragma unroll
    for (int c = 0; c < 2; ++c) {
      int g = c * 256 + t;
      int r = g >> 2, ch = g & 3;
      *(uint4*)&Ash[buf][r * 40 + ch * 8] = av[c];
    }
    #pragma unroll
    for (int c = 0; c < 4; ++c) {
      int g = c * 256 + t;
      int n = g >> 2, ch = g & 3;
      *(uint4*)&Bsh[buf][n * 40 + ch * 8] = bv[c];
    }
  };

  load_tile(0);
  store_tile(0);
  __syncthreads();

  for (int ks = 0; ks < 12; ++ks) {
    const int cur = ks & 1;
    if (ks < 11) load_tile(ks + 1);       // issue globals; waited at store below

    f16x8 af[4], bf[8];
    #pragma unroll
    for (int mt = 0; mt < 4; ++mt)
      af[mt] = *(const f16x8*)&Ash[cur][(rg * 64 + mt * 16 + ml) * 40 + quad * 8];
    #pragma unroll
    for (int nt = 0; nt < 8; ++nt)
      bf[nt] = *(const f16x8*)&Bsh[cur][(cg * 128 + nt * 16 + ml) * 40 + quad * 8];
    #pragma unroll
    for (int mt = 0; mt < 4; ++mt)
      #pragma unroll
      for (int nt = 0; nt < 8; ++nt)
        acc[mt][nt] = __builtin_amdgcn_mfma_f32_16x16x32_f16(af[mt], bf[nt],
                                                             acc[mt][nt], 0, 0, 0);
    if (ks < 11) store_tile(1 - cur);     // other buffer; prior sync protects
    __syncthreads();
  }

  // Epilogue: h = relu(acc + b1[col]); 6 dots over cols; reduce 16 lanes/quad.
  #pragma unroll
  for (int mt = 0; mt < 4; ++mt) {
    float z[4][6];
    #pragma unroll
    for (int rr = 0; rr < 4; ++rr)
      #pragma unroll
      for (int p = 0; p < 6; ++p) z[rr][p] = 0.f;
    #pragma unroll
    for (int nt = 0; nt < 8; ++nt) {
      int col = cg * 128 + nt * 16 + ml;
      float bb = b1[col];
      float wA = w2r[col * 2 + 0];
      float wB = w2r[col * 2 + 1];
      float wC = w2r[512 + col * 2 + 0];
      float wD = w2r[512 + col * 2 + 1];
      float wE = w2s[col * 2 + 0];
      float wF = w2s[col * 2 + 1];
      #pragma unroll
      for (int rr = 0; rr < 4; ++rr) {
        float h = acc[mt][nt][rr] + bb;
        h = h > 0.f ? h : 0.f;
        z[rr][0] = fmaf(h, wA, z[rr][0]);
        z[rr][1] = fmaf(h, wB, z[rr][1]);
        z[rr][2] = fmaf(h, wC, z[rr][2]);
        z[rr][3] = fmaf(h, wD, z[rr][3]);
        z[rr][4] = fmaf(h, wE, z[rr][4]);
        z[rr][5] = fmaf(h, wF, z[rr][5]);
      }
    }
    #pragma unroll
    for (int rr = 0; rr < 4; ++rr)
      #pragma unroll
      for (int p = 0; p < 6; ++p) {
        float v = z[rr][p];
        v += __shfl_xor(v, 1);
        v += __shfl_xor(v, 2);
        v += __shfl_xor(v, 4);
        v += __shfl_xor(v, 8);
        if (ml == 0) zbuf[cg][rg * 64 + mt * 16 + quad * 4 + rr][p] = v;
      }
  }
  __syncthreads();
  for (int i = t; i < 768; i += 256) {
    int r = i / 6, p = i % 6;
    long grow = rowBase + r;
    if (grow < NN) {
      float v = zbuf[0][r][p] + zbuf[1][r][p];
      if (p < 4) z2[grow * 4 + p] = v;
      else       out[grow * 2 + (p - 4)] = v + b2[p - 4];
    }
  }
}

// 4 lanes per node: lane sub handles every-4th edge; reduce over sub.
__global__ void gather2(const float* __restrict__ z2, const int* __restrict__ off,
                        const int* __restrict__ srcs, float* __restrict__ out) {
  int tid = blockIdx.x * blockDim.x + threadIdx.x;
  int n = tid >> 2;
  if (n >= NN) return;
  int sub = tid & 3;
  int e0 = (n == 0) ? 0 : off[2 * n - 1];
  int e1 = off[2 * n];
  int e2 = off[2 * n + 1];
  float o0 = 0.f, o1 = 0.f;
  for (int e = e0 + sub; e < e1; e += 4) {
    float2 v = *(const float2*)(z2 + (long)srcs[e] * 4);
    o0 += v.x; o1 += v.y;
  }
  for (int e = e1 + sub; e < e2; e += 4) {
    float2 v = *(const float2*)(z2 + (long)srcs[e] * 4 + 2);
    o0 += v.x; o1 += v.y;
  }
  o0 += __shfl_xor(o0, 1); o1 += __shfl_xor(o1, 1);
  o0 += __shfl_xor(o0, 2); o1 += __shfl_xor(o1, 2);
  if (sub == 0) {
    out[n * 2 + 0] += o0;
    out[n * 2 + 1] += o1;
  }
}

extern "C" void kernel_launch(void* const* d_in, const int* in_sizes, int n_in,
                              void* d_out, int out_size, void* d_ws, size_t ws_size,
                              hipStream_t stream) {
  const float* x   = (const float*)d_in[0];
  const int*   ei  = (const int*)d_in[1];
  const int*   et  = (const int*)d_in[2];
  const float* w1s = (const float*)d_in[3];
  const float* w1r = (const float*)d_in[4];
  const float* b1  = (const float*)d_in[5];
  const float* w2s = (const float*)d_in[6];
  const float* w2r = (const float*)d_in[7];
  const float* b2  = (const float*)d_in[8];
  float* out = (float*)d_out;
  const int E = in_sizes[2];
  const int* src = ei;
  const int* dst = ei + E;

  f16*   aggh = (f16*)d_ws;                    // NN*256 f16  (51.2 MB)
  f16*   xh   = aggh + (size_t)NN * 256;       // NN*128 f16  (25.6 MB)
  f16*   w1t  = xh + (size_t)NN * 128;         // 12*256*32 f16 (0.2 MB)
  float* z2   = (float*)(w1t + 12 * 256 * 32); // NN*4 f32    (1.6 MB)
  int*   srcs = (int*)(z2 + (size_t)NN * 4);   // E ints      (6.4 MB)
  int*   off  = srcs + E;                      // NR ints     (0.8 MB)
  int*   partials = off + NR;                  // 1024 ints

  zero_i<<<SCAN_BLKS, 256, 0, stream>>>(off, NR);
  hist<<<(E + 255) / 256, 256, 0, stream>>>(dst, et, off, E);
  scan1<<<SCAN_BLKS, 256, 0, stream>>>(off, partials);
  scan2<<<1, 1024, 0, stream>>>(partials);
  scan3<<<SCAN_BLKS, 256, 0, stream>>>(off, partials);
  reorder<<<(E + 255) / 256, 256, 0, stream>>>(src, dst, et, off, srcs, E);

  int n4 = NN * 128 / 4;
  cvt_x<<<(n4 + 255) / 256, 256, 0, stream>>>((const float4*)x, xh, n4);
  cvt_w<<<(12 * 256 * 32 + 255) / 256, 256, 0, stream>>>(w1s, w1r, w1t);

  aggregate<<<(NN * 64 + 255) / 256, 256, 0, stream>>>(xh, off, srcs, aggh);

  gemm_mfma<<<(NN + 127) / 128, 256, 0, stream>>>(xh, aggh, w1t, b1, w2s, w2r, b2,
                                                  z2, out);

  gather2<<<(NN * 4 + 255) / 256, 256, 0, stream>>>(z2, off, srcs, out);
}

// Round 6
// 372.257 us; speedup vs baseline: 9.8022x; 1.3426x over previous
//
#include <hip/hip_runtime.h>

// HGIN_classifier: two relational-GIN layers (R=2), ReLU between.
// R6: replace zero+hist+scan*3+reorder (155us; reorder alone wrote 108MB for
// a 6.4MB payload — random 4B stores cost a 64B line each) with a 2-level
// bucket sort: bucketA (LDS hist) -> bscan -> bucketB (block-reserved runs)
// -> bucketC (1 block/bucket: LDS scan -> CSR off + dense srcs scatter into
// a 13KB single-XCD window). off is START-based with off[NR]=E sentinel.
// Pipeline: zero_small -> bucketA -> bscan -> bucketB -> bucketC
//           cvt_x, cvt_w -> aggregate (f16 gather) -> gemm_mfma -> gather2

typedef _Float16 f16;
typedef _Float16 f16x2 __attribute__((ext_vector_type(2)));
typedef _Float16 f16x4 __attribute__((ext_vector_type(4)));
typedef _Float16 f16x8 __attribute__((ext_vector_type(8)));
typedef float    f32x4 __attribute__((ext_vector_type(4)));

constexpr int NN   = 100000;
constexpr int NR   = NN * 2;     // (node, relation) segments
constexpr int NB   = 512;        // coarse buckets
constexpr int BSH  = 9;          // bucket = seg >> BSH (512 segs/bucket)
constexpr int CHUNK = 8192;      // edges per block in bucketA/B

__global__ void zero_small(int* __restrict__ gcnt) {
  int t = threadIdx.x;
  if (t < NB) gcnt[t] = 0;
}

__global__ void bucketA(const int* __restrict__ dst, const int* __restrict__ et,
                        int* __restrict__ gcnt, int E) {
  __shared__ int h[NB];
  int t = threadIdx.x;
  for (int b = t; b < NB; b += 256) h[b] = 0;
  __syncthreads();
  int lo = blockIdx.x * CHUNK, hi = min(E, lo + CHUNK);
  for (int e = lo + t; e < hi; e += 256)
    atomicAdd(&h[(dst[e] * 2 + et[e]) >> BSH], 1);
  __syncthreads();
  for (int b = t; b < NB; b += 256) {
    int c = h[b];
    if (c) atomicAdd(&gcnt[b], c);
  }
}

__global__ void bscan(const int* __restrict__ gcnt, int* __restrict__ bstart,
                      int* __restrict__ gbase) {  // 1 block, 512 threads
  __shared__ int s[NB];
  int t = threadIdx.x;
  int v = gcnt[t];
  s[t] = v;
  __syncthreads();
  #pragma unroll
  for (int o = 1; o < NB; o <<= 1) {
    int u = (t >= o) ? s[t - o] : 0;
    __syncthreads();
    s[t] += u;
    __syncthreads();
  }
  bstart[t] = s[t] - v;
  gbase[t]  = s[t] - v;
  if (t == NB - 1) bstart[NB] = s[t];
}

__global__ void bucketB(const int* __restrict__ src, const int* __restrict__ dst,
                        const int* __restrict__ et, int* __restrict__ gbase,
                        int2* __restrict__ ebuf, int E) {
  __shared__ int h[NB], base[NB];
  int t = threadIdx.x;
  for (int b = t; b < NB; b += 256) h[b] = 0;
  __syncthreads();
  int lo = blockIdx.x * CHUNK, hi = min(E, lo + CHUNK);
  for (int e = lo + t; e < hi; e += 256)
    atomicAdd(&h[(dst[e] * 2 + et[e]) >> BSH], 1);
  __syncthreads();
  for (int b = t; b < NB; b += 256) {
    int c = h[b];
    base[b] = c ? atomicAdd(&gbase[b], c) : 0;
    h[b] = 0;
  }
  __syncthreads();
  for (int e = lo + t; e < hi; e += 256) {
    int seg = dst[e] * 2 + et[e];
    int b = seg >> BSH;
    int r = atomicAdd(&h[b], 1);
    ebuf[base[b] + r] = make_int2(src[e], seg);
  }
}

// One block per bucket: build CSR off for its 512 segs + dense srcs scatter.
__global__ void bucketC(const int2* __restrict__ ebuf, const int* __restrict__ bstart,
                        int* __restrict__ off, int* __restrict__ srcs) {
  __shared__ int sh[NB], soff[NB], cnt[NB], tmp[256];
  int b = blockIdx.x, t = threadIdx.x;
  int lo = bstart[b], hi = bstart[b + 1];
  for (int s0 = t; s0 < NB; s0 += 256) { sh[s0] = 0; cnt[s0] = 0; }
  __syncthreads();
  for (int e = lo + t; e < hi; e += 256)
    atomicAdd(&sh[ebuf[e].y - (b << BSH)], 1);
  __syncthreads();
  int a0 = sh[2 * t], a1 = sh[2 * t + 1];
  tmp[t] = a0 + a1;
  __syncthreads();
  #pragma unroll
  for (int o = 1; o < 256; o <<= 1) {
    int u = (t >= o) ? tmp[t - o] : 0;
    __syncthreads();
    tmp[t] += u;
    __syncthreads();
  }
  int ex = tmp[t] - (a0 + a1);
  soff[2 * t] = ex;
  soff[2 * t + 1] = ex + a0;
  __syncthreads();
  int g0 = (b << BSH) + 2 * t;
  if (g0 <= NR)     off[g0]     = lo + soff[2 * t];
  if (g0 + 1 <= NR) off[g0 + 1] = lo + soff[2 * t + 1];
  for (int e = lo + t; e < hi; e += 256) {
    int2 p = ebuf[e];
    int s = p.y - (b << BSH);
    int r = atomicAdd(&cnt[s], 1);
    srcs[lo + soff[s] + r] = p.x;
  }
}

__global__ void cvt_x(const float4* __restrict__ xf, f16* __restrict__ xh, int n4) {
  int i = blockIdx.x * blockDim.x + threadIdx.x;
  if (i >= n4) return;
  float4 v = xf[i];
  f16x4 h;
  h.x = (f16)v.x; h.y = (f16)v.y; h.z = (f16)v.z; h.w = (f16)v.w;
  *(f16x4*)(xh + (size_t)i * 4) = h;
}

// k-step-major repack: w1t[ks][n][ki] = f16(W[ks*32+ki][n]).
__global__ void cvt_w(const float* __restrict__ w1s, const float* __restrict__ w1r,
                      f16* __restrict__ w1t) {
  int id = blockIdx.x * blockDim.x + threadIdx.x;
  if (id >= 12 * 256 * 32) return;
  int ks = id >> 13, rem = id & 8191;
  int n = rem >> 5, ki = rem & 31;
  int k = ks * 32 + ki;
  float v = (k < 128) ? w1s[k * 256 + n] : w1r[(k - 128) * 256 + n];
  w1t[id] = (f16)v;
}

// One wave per node; lane l owns cols 2l,2l+1; unroll x4 for outstanding loads.
__global__ void aggregate(const f16* __restrict__ xh, const int* __restrict__ off,
                          const int* __restrict__ srcs, f16* __restrict__ aggh) {
  int w = (blockIdx.x * blockDim.x + threadIdx.x) >> 6;
  if (w >= NN) return;
  int lane = threadIdx.x & 63;
  int e0 = off[2 * w];
  int e1 = off[2 * w + 1];
  int e2 = off[2 * w + 2];
  float a0 = 0.f, a1 = 0.f, c0 = 0.f, c1 = 0.f;
  int e = e0;
  for (; e + 3 < e1; e += 4) {
    f16x2 v0 = *(const f16x2*)(xh + (long)srcs[e] * 128 + lane * 2);
    f16x2 v1 = *(const f16x2*)(xh + (long)srcs[e + 1] * 128 + lane * 2);
    f16x2 v2 = *(const f16x2*)(xh + (long)srcs[e + 2] * 128 + lane * 2);
    f16x2 v3 = *(const f16x2*)(xh + (long)srcs[e + 3] * 128 + lane * 2);
    a0 += (float)v0.x + (float)v1.x + (float)v2.x + (float)v3.x;
    a1 += (float)v0.y + (float)v1.y + (float)v2.y + (float)v3.y;
  }
  for (; e < e1; ++e) {
    f16x2 v = *(const f16x2*)(xh + (long)srcs[e] * 128 + lane * 2);
    a0 += (float)v.x; a1 += (float)v.y;
  }
  e = e1;
  for (; e + 3 < e2; e += 4) {
    f16x2 v0 = *(const f16x2*)(xh + (long)srcs[e] * 128 + lane * 2);
    f16x2 v1 = *(const f16x2*)(xh + (long)srcs[e + 1] * 128 + lane * 2);
    f16x2 v2 = *(const f16x2*)(xh + (long)srcs[e + 2] * 128 + lane * 2);
    f16x2 v3 = *(const f16x2*)(xh + (long)srcs[e + 3] * 128 + lane * 2);
    c0 += (float)v0.x + (float)v1.x + (float)v2.x + (float)v3.x;
    c1 += (float)v0.y + (float)v1.y + (float)v2.y + (float)v3.y;
  }
  for (; e < e2; ++e) {
    f16x2 v = *(const f16x2*)(xh + (long)srcs[e] * 128 + lane * 2);
    c0 += (float)v.x; c1 += (float)v.y;
  }
  f16* row = aggh + (long)w * 256;
  f16x2 o0; o0.x = (f16)a0; o0.y = (f16)a1;
  f16x2 o1; o1.x = (f16)c0; o1.y = (f16)c1;
  *(f16x2*)(row + lane * 2) = o0;
  *(f16x2*)(row + 128 + lane * 2) = o1;
}

// Fused layer-1 GEMM (f16 MFMA) + layer-2 transform epilogue.
// 128 rows x 256 cols per block; 4 waves, wave = 64 rows x 128 cols.
// LDS double-buffered, register prefetch; ONE barrier per iter.
__global__ __launch_bounds__(256, 2) void gemm_mfma(
    const f16* __restrict__ xh, const f16* __restrict__ aggh,
    const f16* __restrict__ w1t,
    const float* __restrict__ b1, const float* __restrict__ w2s,
    const float* __restrict__ w2r, const float* __restrict__ b2,
    float* __restrict__ z2, float* __restrict__ out) {
  __shared__ __align__(16) f16 Ash[2][128 * 40];
  __shared__ __align__(16) f16 Bsh[2][256 * 40];
  __shared__ float zbuf[2][128][6];
  const int t = threadIdx.x;
  const long rowBase = (long)blockIdx.x * 128;
  const int lane = t & 63, wv = t >> 6;
  const int rg = wv >> 1, cg = wv & 1;
  const int ml = lane & 15, quad = lane >> 4;

  f32x4 acc[4][8];
  #pragma unroll
  for (int mt = 0; mt < 4; ++mt)
    #pragma unroll
    for (int nt = 0; nt < 8; ++nt) acc[mt][nt] = (f32x4)(0.f);

  uint4 av[2], bv[4];
  auto load_tile = [&](int ks) {
    const int kt = ks * 32;
    #pragma unroll
    for (int c = 0; c < 2; ++c) {
      int g = c * 256 + t;
      int r = g >> 2, ch = g & 3;
      long grow = rowBase + r;
      if (grow < NN) {
        int k0 = kt + ch * 8;
        const f16* ap = (kt < 128) ? (xh + grow * 128 + k0)
                                   : (aggh + grow * 256 + (k0 - 128));
        av[c] = *(const uint4*)ap;
      } else {
        av[c] = make_uint4(0, 0, 0, 0);
      }
    }
    const uint4* bp = (const uint4*)(w1t + (long)ks * 8192) + t;
    #pragma unroll
    for (int c = 0; c < 4; ++c) bv[c] = bp[c * 256];
  };
  auto store_tile = [&](int buf) {
    #pragma unroll
    for (int c = 0; c < 2; ++c) {
      int g = c * 256 + t;
      int r = g >> 2, ch = g & 3;
      *(uint4*)&Ash[buf][r * 40 + ch * 8] = av[c];
    }
    #pragma unroll
    for (int c = 0; c < 4; ++c) {
      int g = c * 256 + t;
      int n = g >> 2, ch = g & 3;
      *(uint4*)&Bsh[buf][n * 40 + ch * 8] = bv[c];
    }
  };

  load_tile(0);
  store_tile(0);
  __syncthreads();

  for (int ks = 0; ks < 12; ++ks) {
    const int cur = ks & 1;
    if (ks < 11) load_tile(ks + 1);

    f16x8 af[4], bf[8];
    #pragma unroll
    for (int mt = 0; mt < 4; ++mt)
      af[mt] = *(const f16x8*)&Ash[cur][(rg * 64 + mt * 16 + ml) * 40 + quad * 8];
    #pragma unroll
    for (int nt = 0; nt < 8; ++nt)
      bf[nt] = *(const f16x8*)&Bsh[cur][(cg * 128 + nt * 16 + ml) * 40 + quad * 8];
    #pragma unroll
    for (int mt = 0; mt < 4; ++mt)
      #pragma unroll
      for (int nt = 0; nt < 8; ++nt)
        acc[mt][nt] = __builtin_amdgcn_mfma_f32_16x16x32_f16(af[mt], bf[nt],
                                                             acc[mt][nt], 0, 0, 0);
    if (ks < 11) store_tile(1 - cur);
    __syncthreads();
  }

  #pragma unroll
  for (int mt = 0; mt < 4; ++mt) {
    float z[4][6];
    #pragma unroll
    for (int rr = 0; rr < 4; ++rr)
      #pragma unroll
      for (int p = 0; p < 6; ++p) z[rr][p] = 0.f;
    #pragma unroll
    for (int nt = 0; nt < 8; ++nt) {
      int col = cg * 128 + nt * 16 + ml;
      float bb = b1[col];
      float wA = w2r[col * 2 + 0];
      float wB = w2r[col * 2 + 1];
      float wC = w2r[512 + col * 2 + 0];
      float wD = w2r[512 + col * 2 + 1];
      float wE = w2s[col * 2 + 0];
      float wF = w2s[col * 2 + 1];
      #pragma unroll
      for (int rr = 0; rr < 4; ++rr) {
        float h = acc[mt][nt][rr] + bb;
        h = h > 0.f ? h : 0.f;
        z[rr][0] = fmaf(h, wA, z[rr][0]);
        z[rr][1] = fmaf(h, wB, z[rr][1]);
        z[rr][2] = fmaf(h, wC, z[rr][2]);
        z[rr][3] = fmaf(h, wD, z[rr][3]);
        z[rr][4] = fmaf(h, wE, z[rr][4]);
        z[rr][5] = fmaf(h, wF, z[rr][5]);
      }
    }
    #pragma unroll
    for (int rr = 0; rr < 4; ++rr)
      #pragma unroll
      for (int p = 0; p < 6; ++p) {
        float v = z[rr][p];
        v += __shfl_xor(v, 1);
        v += __shfl_xor(v, 2);
        v += __shfl_xor(v, 4);
        v += __shfl_xor(v, 8);
        if (ml == 0) zbuf[cg][rg * 64 + mt * 16 + quad * 4 + rr][p] = v;
      }
  }
  __syncthreads();
  for (int i = t; i < 768; i += 256) {
    int r = i / 6, p = i % 6;
    long grow = rowBase + r;
    if (grow < NN) {
      float v = zbuf[0][r][p] + zbuf[1][r][p];
      if (p < 4) z2[grow * 4 + p] = v;
      else       out[grow * 2 + (p - 4)] = v + b2[p - 4];
    }
  }
}

// 4 lanes per node: lane sub handles every-4th edge; reduce over sub.
__global__ void gather2(const float* __restrict__ z2, const int* __restrict__ off,
                        const int* __restrict__ srcs, float* __restrict__ out) {
  int tid = blockIdx.x * blockDim.x + threadIdx.x;
  int n = tid >> 2;
  if (n >= NN) return;
  int sub = tid & 3;
  int e0 = off[2 * n];
  int e1 = off[2 * n + 1];
  int e2 = off[2 * n + 2];
  float o0 = 0.f, o1 = 0.f;
  for (int e = e0 + sub; e < e1; e += 4) {
    float2 v = *(const float2*)(z2 + (long)srcs[e] * 4);
    o0 += v.x; o1 += v.y;
  }
  for (int e = e1 + sub; e < e2; e += 4) {
    float2 v = *(const float2*)(z2 + (long)srcs[e] * 4 + 2);
    o0 += v.x; o1 += v.y;
  }
  o0 += __shfl_xor(o0, 1); o1 += __shfl_xor(o1, 1);
  o0 += __shfl_xor(o0, 2); o1 += __shfl_xor(o1, 2);
  if (sub == 0) {
    out[n * 2 + 0] += o0;
    out[n * 2 + 1] += o1;
  }
}

extern "C" void kernel_launch(void* const* d_in, const int* in_sizes, int n_in,
                              void* d_out, int out_size, void* d_ws, size_t ws_size,
                              hipStream_t stream) {
  const float* x   = (const float*)d_in[0];
  const int*   ei  = (const int*)d_in[1];
  const int*   et  = (const int*)d_in[2];
  const float* w1s = (const float*)d_in[3];
  const float* w1r = (const float*)d_in[4];
  const float* b1  = (const float*)d_in[5];
  const float* w2s = (const float*)d_in[6];
  const float* w2r = (const float*)d_in[7];
  const float* b2  = (const float*)d_in[8];
  float* out = (float*)d_out;
  const int E = in_sizes[2];
  const int* src = ei;
  const int* dst = ei + E;

  f16*   aggh = (f16*)d_ws;                      // NN*256 f16   (51.2 MB)
  f16*   xh   = aggh + (size_t)NN * 256;         // NN*128 f16   (25.6 MB)
  f16*   w1t  = xh + (size_t)NN * 128;           // 12*256*32 f16 (0.2 MB)
  float* z2   = (float*)(w1t + 12 * 256 * 32);   // NN*4 f32     (1.6 MB)
  int2*  ebuf = (int2*)(z2 + (size_t)NN * 4);    // E int2       (12.8 MB)
  int*   srcs = (int*)(ebuf + E);                // E int        (6.4 MB)
  int*   off  = srcs + E;                        // NR+1 int     (0.8 MB)
  int*   gcnt = off + NR + 1;                    // NB int
  int*   bstart = gcnt + NB;                     // NB+1 int
  int*   gbase  = bstart + NB + 1;               // NB int

  int nblk = (E + CHUNK - 1) / CHUNK;
  zero_small<<<1, 512, 0, stream>>>(gcnt);
  bucketA<<<nblk, 256, 0, stream>>>(dst, et, gcnt, E);
  bscan<<<1, 512, 0, stream>>>(gcnt, bstart, gbase);
  bucketB<<<nblk, 256, 0, stream>>>(src, dst, et, gbase, ebuf, E);
  bucketC<<<NB, 256, 0, stream>>>(ebuf, bstart, off, srcs);

  int n4 = NN * 128 / 4;
  cvt_x<<<(n4 + 255) / 256, 256, 0, stream>>>((const float4*)x, xh, n4);
  cvt_w<<<(12 * 256 * 32 + 255) / 256, 256, 0, stream>>>(w1s, w1r, w1t);

  aggregate<<<(NN * 64 + 255) / 256, 256, 0, stream>>>(xh, off, srcs, aggh);

  gemm_mfma<<<(NN + 127) / 128, 256, 0, stream>>>(xh, aggh, w1t, b1, w2s, w2r, b2,
                                                  z2, out);

  gather2<<<(NN * 4 + 255) / 256, 256, 0, stream>>>(z2, off, srcs, out);
}